// Round 9
// baseline (58.999 us; speedup 1.0000x reference)
//
#include <hip/hip_runtime.h>

#define C_TOT 64
#define Dd 48
#define Hh 128
#define Ww 128
#define HW (Hh*Ww)
#define DHW (Dd*HW)
#define CSPLIT 8
#define SROW 37             // stage row stride (floats), odd => bank spread
#define NPL 14              // max staged z-planes (rd<=12)
#define HALF (NPL*34*SROW)  // floats per stage buffer

typedef float lf2 __attribute__((ext_vector_type(2), aligned(4)));

__device__ __forceinline__ void axis_interp(float c, int dim, int& lo, int& hi,
                                            float& fr, bool& valid) {
    valid = (c >= -1.0f) && (c <= (float)dim);
    c = fminf(fmaxf(c, 0.0f), (float)(dim - 1));
    float l = floorf(c);
    lo = (int)l;
    hi = min(lo + 1, dim - 1);
    fr = c - l;
}

// One DMA per (plane,row): LDS dest = uniform row base + lane*4 (m104 contract),
// global src = row start + lane (per-lane). No VGPR staging state.
__device__ __forceinline__ void gll_dword(const float* g, float* l) {
    __builtin_amdgcn_global_load_lds(
        (const __attribute__((address_space(1))) float*)g,
        (__attribute__((address_space(3))) float*)l, 4, 0, 0);
}

__device__ __forceinline__ void issue_stage(const float* gc, float* stg,
                                            int p0, int pext, int y0, int yext,
                                            int x0, int xext, int wave, int lane)
{
    if (lane < xext) {
        for (int p = 0; p < pext; ++p) {
            const float* gplane = gc + (size_t)(p0 + p) * HW + (size_t)y0 * Ww + x0 + lane;
            float* splane = stg + p * 34 * SROW;
            for (int yy = wave; yy < yext; yy += 16)
                gll_dword(gplane + yy * Ww, splane + yy * SROW);
        }
    }
}

__global__ __launch_bounds__(1024, 2) void roialign_avg3d_kernel(
    const float* __restrict__ feats, const float* __restrict__ rois,
    float* __restrict__ out)
{
    const int r    = blockIdx.x;   // roi
    const int cb   = blockIdx.y;   // channel octet
    const int tid  = threadIdx.x;
    const int zs   = tid >> 6;     // wave = z-sample 0..15
    const int lane = tid & 63;
    const int xb   = lane & 7;     // x-bin (covers both its x-samples)
    const int ysi  = lane >> 3;    // y-sample sub-index 0..7

    __shared__ float stage[2 * HALF];          // 140896 B (double buffer)
    __shared__ float bins[16 * 64];            // 4096 B

    // --- roi params (block-uniform) ---
    const float* rr = rois + r * 7;
    const int   b  = (int)rr[0];
    const float x1 = rr[1]*0.25f, y1v = rr[2]*0.25f, z1v = rr[3]*0.25f;
    const float x2 = rr[4]*0.25f, y2v = rr[5]*0.25f, z2v = rr[6]*0.25f;
    const float rw = fmaxf(x2-x1, 1.0f), rh = fmaxf(y2v-y1v, 1.0f), rd = fmaxf(z2v-z1v, 1.0f);
    const float bsx = rw*0.125f, bsy = rh*0.125f, bsz = rd*0.125f;

    // --- staged window (full roi sub-volume, all 16 z-samples) ---
    const float xc0f = x1 + 0.25f*bsx, xc15f = x1 + 7.75f*bsx;
    int x0   = (int)floorf(fminf(fmaxf(xc0f, 0.0f), 127.0f));
    int xhiR = min((int)floorf(fminf(fmaxf(xc15f, 0.0f), 127.0f)) + 1, Ww-1);
    int xext = xhiR - x0 + 1;
    if (xext < 4) xext = 4;
    if (x0 + xext > Ww) x0 = Ww - xext;

    const float yc0f = y1v + 0.25f*bsy, yc15f = y1v + 7.75f*bsy;
    const int y0   = (int)floorf(fminf(fmaxf(yc0f, 0.0f), 127.0f));
    const int yhiR = min((int)floorf(fminf(fmaxf(yc15f, 0.0f), 127.0f)) + 1, Hh-1);
    const int yext = yhiR - y0 + 1;

    const float zc0f = z1v + 0.25f*bsz, zc15f = z1v + 7.75f*bsz;
    const int p0   = (int)floorf(fminf(fmaxf(zc0f, 0.0f), 47.0f));
    const int phiR = min((int)floorf(fminf(fmaxf(zc15f, 0.0f), 47.0f)) + 1, Dd-1);
    const int pext = phiR - p0 + 1;            // <= 14

    const float* fb = feats + (size_t)(b*C_TOT + cb*CSPLIT) * (size_t)DHW;

    // --- issue channel-0 staging DMA immediately (into buffer 0);
    //     latency hides under the lane-geometry VALU below ---
    issue_stage(fb, stage, p0, pext, y0, yext, x0, xext, zs, lane);

    // --- x window weights (lane-fixed) ---
    const float xcA = x1 + (float)xb*bsx + 0.25f*bsx;
    const float xcB = x1 + (float)xb*bsx + 0.75f*bsx;
    int xloA,xhiA,xloB,xhiB; float fxA,fxB; bool vxA,vxB;
    axis_interp(xcA, Ww, xloA, xhiA, fxA, vxA);
    axis_interp(xcB, Ww, xloB, xhiB, fxB, vxB);
    const int bAbs = min(xloA, x0 + xext - 4);
    const int bx   = bAbs - x0;
    float w0=0.f, w1=0.f, w2=0.f, w3=0.f;
    {
        const int iA = xloA-bAbs, hA = xhiA-bAbs, iB = xloB-bAbs, hB = xhiB-bAbs;
        const float a0 = vxA ? (1.0f-fxA) : 0.0f, a1 = vxA ? fxA : 0.0f;
        const float b0 = vxB ? (1.0f-fxB) : 0.0f, b1 = vxB ? fxB : 0.0f;
        w0 += (iA==0)?a0:0.f; w1 += (iA==1)?a0:0.f; w2 += (iA==2)?a0:0.f; w3 += (iA==3)?a0:0.f;
        w0 += (hA==0)?a1:0.f; w1 += (hA==1)?a1:0.f; w2 += (hA==2)?a1:0.f; w3 += (hA==3)?a1:0.f;
        w0 += (iB==0)?b0:0.f; w1 += (iB==1)?b0:0.f; w2 += (iB==2)?b0:0.f; w3 += (iB==3)?b0:0.f;
        w0 += (hB==0)?b1:0.f; w1 += (hB==1)?b1:0.f; w2 += (hB==2)?b1:0.f; w3 += (hB==3)?b1:0.f;
    }

    // --- z interp (per wave) ---
    const float zc = z1v + (float)(zs>>1)*bsz + ((float)(zs&1)+0.5f)*0.5f*bsz;
    int zlo,zhi; float fz; bool vz;
    axis_interp(zc, Dd, zlo, zhi, fz, vz);
    const float wz0 = 1.0f - fz, wz1 = fz;
    const int pz0 = zlo - p0, pz1 = zhi - p0;

    // --- y interp, both yy groups (lane+wave fixed) ---
    float wrow[2][4];
    int   adr[2][4];
    #pragma unroll
    for (int yy = 0; yy < 2; ++yy) {
        const int ys = yy*8 + ysi;
        const float yc = y1v + (float)(ys>>1)*bsy + ((float)(ys&1)+0.5f)*0.5f*bsy;
        int ylo,yhi; float fy; bool vy;
        axis_interp(yc, Hh, ylo, yhi, fy, vy);
        const int ly0 = ylo - y0, ly1 = yhi - y0;
        const float s = (vy && vz) ? 1.0f : 0.0f;
        const float wy0 = 1.0f - fy, wy1 = fy;
        wrow[yy][0] = s*wz0*wy0; wrow[yy][1] = s*wz0*wy1;
        wrow[yy][2] = s*wz1*wy0; wrow[yy][3] = s*wz1*wy1;
        adr[yy][0] = (pz0*34 + ly0)*SROW + bx;
        adr[yy][1] = (pz0*34 + ly1)*SROW + bx;
        adr[yy][2] = (pz1*34 + ly0)*SROW + bx;
        adr[yy][3] = (pz1*34 + ly1)*SROW + bx;
    }

    asm volatile("s_waitcnt vmcnt(0)" ::: "memory");  // own ch-0 DMAs landed
    __syncthreads();                                  // everyone's landed

    for (int c = 0; c < CSPLIT; ++c) {
        float* cur = stage + ((c & 1) ? HALF : 0);
        float* nxt = stage + ((c & 1) ? 0 : HALF);

        // --- issue channel c+1 DMA into the other buffer FIRST:
        //     it flies during the whole sample+pool phase below ---
        if (c + 1 < CSPLIT)
            issue_stage(fb + (size_t)(c+1)*DHW, nxt, p0, pext, y0, yext, x0, xext, zs, lane);

        // --- sample channel c from LDS: 2 bin-samples per lane ---
        #pragma unroll
        for (int yy = 0; yy < 2; ++yy) {
            float v = 0.0f;
            #pragma unroll
            for (int rq = 0; rq < 4; ++rq) {
                const float* sp = cur + adr[yy][rq];
                lf2 u0 = *(const lf2*)sp;
                lf2 u1 = *(const lf2*)(sp+2);
                v += wrow[yy][rq] * (u0.x*w0 + u0.y*w1 + u1.x*w2 + u1.y*w3);
            }
            v += __shfl_xor(v, 8);           // reduce y-sample pair
            if (!(ysi & 1)) {
                const int yb = yy*4 + (ysi>>1);
                bins[zs*64 + yb*8 + xb] = v;
            }
        }
        __syncthreads();   // bins ready (DMA still in flight)

        // --- pool+store c (343 threads), overlapped with the DMA ---
        if (tid < 343) {
            const int w_ = tid % 7, h_ = (tid/7) % 7, dz = tid/49;
            float acc = 0.0f;
            #pragma unroll
            for (int g = 0; g < 4; ++g) {
                const float* bz = &bins[(2*dz+g)*64];
                acc += bz[h_*8+w_]       + bz[h_*8+w_+1]
                     + bz[(h_+1)*8+w_]   + bz[(h_+1)*8+w_+1];
            }
            acc *= (1.0f/64.0f);
            const int cg = cb*CSPLIT + c;
            out[(((size_t)r*C_TOT + cg)*7 + dz)*49 + h_*7 + w_] = acc;
        }

        asm volatile("s_waitcnt vmcnt(0)" ::: "memory");  // own c+1 DMAs landed
        __syncthreads();                                  // all landed; bins consumed
    }
}

extern "C" void kernel_launch(void* const* d_in, const int* in_sizes, int n_in,
                              void* d_out, int out_size, void* d_ws, size_t ws_size,
                              hipStream_t stream) {
    const float* feats = (const float*)d_in[0];
    const float* rois  = (const float*)d_in[1];
    float* out = (float*)d_out;
    const int R = in_sizes[1] / 7;   // 64
    dim3 grid(R, C_TOT / CSPLIT);
    roialign_avg3d_kernel<<<grid, 1024, 0, stream>>>(feats, rois, out);
}

// Round 10
// 42.156 us; speedup vs baseline: 1.3996x; 1.3996x over previous
//
#include <hip/hip_runtime.h>

#define C_TOT 64
#define Dd 48
#define Hh 128
#define Ww 128
#define HW (Hh*Ww)
#define DHW (Dd*HW)
#define CSPLIT 8            // channels per block
#define CPAD  (CSPLIT + 1)  // LDS pad

// 4-float vector, 4-byte aligned: one gather covers both x-samples of a bin
typedef float f4v __attribute__((ext_vector_type(4), aligned(4)));

__device__ __forceinline__ void axis_interp(float c, int dim, int& lo, int& hi,
                                            float& fr, bool& valid) {
    valid = (c >= -1.0f) && (c <= (float)dim);
    c = fminf(fmaxf(c, 0.0f), (float)(dim - 1));
    float l = floorf(c);
    lo = (int)l;
    hi = min(lo + 1, dim - 1);
    fr = c - l;
}

__global__ __launch_bounds__(1024, 8) void roialign_avg3d_kernel(
    const float* __restrict__ feats, const float* __restrict__ rois,
    float* __restrict__ out)
{
    const int r    = blockIdx.x;   // roi
    const int cb   = blockIdx.y;   // channel octet 0..7
    const int tid  = threadIdx.x;
    const int zs   = tid >> 6;     // wave = z-sample 0..15
    const int lane = tid & 63;
    const int xb   = lane & 7;     // x-bin (lane handles BOTH its x-samples)
    const int ysi  = lane >> 3;    // y-sample sub-index 0..7

    // bins[z-sample][yb][xb][c] — written exactly once per (bin, channel)
    __shared__ float bins[16][8][8][CPAD];

    // --- roi params (uniform per block) ---
    const float* rr = rois + r * 7;
    const int   b  = (int)rr[0];
    const float x1 = rr[1] * 0.25f, y1v = rr[2] * 0.25f, z1v = rr[3] * 0.25f;
    const float x2 = rr[4] * 0.25f, y2v = rr[5] * 0.25f, z2v = rr[6] * 0.25f;
    const float rw = fmaxf(x2 - x1, 1.0f);
    const float rh = fmaxf(y2v - y1v, 1.0f);
    const float rd = fmaxf(z2v - z1v, 1.0f);
    const float bsx = rw * 0.125f, bsy = rh * 0.125f, bsz = rd * 0.125f;

    // --- x geometry (lane-fixed): both samples of bin xb folded into a
    //     4-wide weight vector against the dwordx4 window at `base` ---
    const float xcA = x1 + (float)xb * bsx + 0.25f * bsx;
    const float xcB = x1 + (float)xb * bsx + 0.75f * bsx;
    int xloA, xhiA, xloB, xhiB; float fxA, fxB; bool vxA, vxB;
    axis_interp(xcA, Ww, xloA, xhiA, fxA, vxA);
    axis_interp(xcB, Ww, xloB, xhiB, fxB, vxB);
    const int base = min(xloA, Ww - 4);   // covers xloA..xhiB, stays in-bounds
    float w0 = 0.0f, w1 = 0.0f, w2 = 0.0f, w3 = 0.0f;
    {
        const int iA = xloA - base, hA = xhiA - base;
        const int iB = xloB - base, hB = xhiB - base;
        const float a0 = vxA ? (1.0f - fxA) : 0.0f, a1 = vxA ? fxA : 0.0f;
        const float b0 = vxB ? (1.0f - fxB) : 0.0f, b1 = vxB ? fxB : 0.0f;
        w0 += (iA == 0) ? a0 : 0.0f; w1 += (iA == 1) ? a0 : 0.0f; w2 += (iA == 2) ? a0 : 0.0f; w3 += (iA == 3) ? a0 : 0.0f;
        w0 += (hA == 0) ? a1 : 0.0f; w1 += (hA == 1) ? a1 : 0.0f; w2 += (hA == 2) ? a1 : 0.0f; w3 += (hA == 3) ? a1 : 0.0f;
        w0 += (iB == 0) ? b0 : 0.0f; w1 += (iB == 1) ? b0 : 0.0f; w2 += (iB == 2) ? b0 : 0.0f; w3 += (iB == 3) ? b0 : 0.0f;
        w0 += (hB == 0) ? b1 : 0.0f; w1 += (hB == 1) ? b1 : 0.0f; w2 += (hB == 2) ? b1 : 0.0f; w3 += (hB == 3) ? b1 : 0.0f;
    }

    // --- z interp (fixed per wave) ---
    const float zc = z1v + (float)(zs >> 1) * bsz + ((float)(zs & 1) + 0.5f) * 0.5f * bsz;
    int zlo, zhi; float fz; bool vz;
    axis_interp(zc, Dd, zlo, zhi, fz, vz);
    const float wz0 = 1.0f - fz, wz1 = fz;
    const int zrow0 = zlo * Hh, zrow1 = zhi * Hh;

    // --- y geometry, both groups, hoisted (lane+wave fixed) ---
    float wr[2][4];
    int   off[2][4];
    #pragma unroll
    for (int yy = 0; yy < 2; ++yy) {
        const int ys = 8 * yy + ysi;
        const float yc = y1v + (float)(ys >> 1) * bsy + ((float)(ys & 1) + 0.5f) * 0.5f * bsy;
        int ylo, yhi; float fy; bool vy;
        axis_interp(yc, Hh, ylo, yhi, fy, vy);
        const float s = (vy && vz) ? 1.0f : 0.0f;
        const float wy0 = 1.0f - fy, wy1 = fy;
        wr[yy][0] = s * wz0 * wy0; wr[yy][1] = s * wz0 * wy1;
        wr[yy][2] = s * wz1 * wy0; wr[yy][3] = s * wz1 * wy1;
        off[yy][0] = (zrow0 + ylo) * Ww + base;
        off[yy][1] = (zrow0 + yhi) * Ww + base;
        off[yy][2] = (zrow1 + ylo) * Ww + base;
        off[yy][3] = (zrow1 + yhi) * Ww + base;
    }

    const float* fb = feats + (size_t)(b * C_TOT + cb * CSPLIT) * (size_t)DHW;
    const bool writer = !(ysi & 1);
    const int  ybl    = ysi >> 1;   // yb = 4*yy + ybl

    const float* p = fb;
    for (int c = 0; c < CSPLIT; ++c, p += DHW) {
        // batch-issue all 8 row loads (both y-groups) for channel c
        f4v ra0 = *(const f4v*)(p + off[0][0]);
        f4v ra1 = *(const f4v*)(p + off[0][1]);
        f4v ra2 = *(const f4v*)(p + off[0][2]);
        f4v ra3 = *(const f4v*)(p + off[0][3]);
        f4v rb0 = *(const f4v*)(p + off[1][0]);
        f4v rb1 = *(const f4v*)(p + off[1][1]);
        f4v rb2 = *(const f4v*)(p + off[1][2]);
        f4v rb3 = *(const f4v*)(p + off[1][3]);

        float va = wr[0][0] * (ra0.x*w0 + ra0.y*w1 + ra0.z*w2 + ra0.w*w3)
                 + wr[0][1] * (ra1.x*w0 + ra1.y*w1 + ra1.z*w2 + ra1.w*w3)
                 + wr[0][2] * (ra2.x*w0 + ra2.y*w1 + ra2.z*w2 + ra2.w*w3)
                 + wr[0][3] * (ra3.x*w0 + ra3.y*w1 + ra3.z*w2 + ra3.w*w3);
        float vb = wr[1][0] * (rb0.x*w0 + rb0.y*w1 + rb0.z*w2 + rb0.w*w3)
                 + wr[1][1] * (rb1.x*w0 + rb1.y*w1 + rb1.z*w2 + rb1.w*w3)
                 + wr[1][2] * (rb2.x*w0 + rb2.y*w1 + rb2.z*w2 + rb2.w*w3)
                 + wr[1][3] * (rb3.x*w0 + rb3.y*w1 + rb3.z*w2 + rb3.w*w3);

        va += __shfl_xor(va, 8);   // reduce y-sample pair (group 0)
        vb += __shfl_xor(vb, 8);   // reduce y-sample pair (group 1)
        if (writer) {
            bins[zs][ybl    ][xb][c] = va;
            bins[zs][4 + ybl][xb][c] = vb;
        }
    }
    __syncthreads();

    // --- fused pooling: out(dz,h,w) = (1/64) * sum over 4 z-slices, 2 yb, 2 xb ---
    for (int i = tid; i < CSPLIT * 7 * 7 * 7; i += 1024) {
        const int w  = i % 7;
        const int h  = (i / 7) % 7;
        const int dz = (i / 49) % 7;
        const int c  = i / 343;
        float acc = 0.0f;
        #pragma unroll
        for (int g = 0; g < 4; ++g) {
            const int z = 2 * dz + g;
            acc += bins[z][h    ][w][c] + bins[z][h    ][w + 1][c]
                 + bins[z][h + 1][w][c] + bins[z][h + 1][w + 1][c];
        }
        acc *= (1.0f / 64.0f);
        const int cg = cb * CSPLIT + c;
        out[((((size_t)r * C_TOT + cg) * 7 + dz) * 7 + h) * 7 + w] = acc;
    }
}

extern "C" void kernel_launch(void* const* d_in, const int* in_sizes, int n_in,
                              void* d_out, int out_size, void* d_ws, size_t ws_size,
                              hipStream_t stream) {
    const float* feats = (const float*)d_in[0];
    const float* rois  = (const float*)d_in[1];
    float* out = (float*)d_out;
    const int R = in_sizes[1] / 7;   // 64
    dim3 grid(R, C_TOT / CSPLIT);
    roialign_avg3d_kernel<<<grid, 1024, 0, stream>>>(feats, rois, out);
}

// Round 11
// 32.278 us; speedup vs baseline: 1.8279x; 1.3060x over previous
//
#include <hip/hip_runtime.h>

#define C_TOT 64
#define Dd 48
#define Hh 128
#define Ww 128
#define HW (Hh*Ww)
#define DHW (Dd*HW)
#define CSPLIT 8            // channels per block
#define CPAD  (CSPLIT + 1)  // bins LDS pad
#define NPL 14              // max unique z-planes per roi window

typedef float f4v __attribute__((ext_vector_type(4), aligned(4)));

__device__ __forceinline__ void axis_interp(float c, int dim, int& lo, int& hi,
                                            float& fr, bool& valid) {
    valid = (c >= -1.0f) && (c <= (float)dim);
    c = fminf(fmaxf(c, 0.0f), (float)(dim - 1));
    float l = floorf(c);
    lo = (int)l;
    hi = min(lo + 1, dim - 1);
    fr = c - l;
}

__device__ __forceinline__ float dot4(f4v v, float w0, float w1, float w2, float w3) {
    return v.x * w0 + v.y * w1 + v.z * w2 + v.w * w3;
}

__global__ __launch_bounds__(1024, 8) void roialign_avg3d_kernel(
    const float* __restrict__ feats, const float* __restrict__ rois,
    float* __restrict__ out)
{
    const int r    = blockIdx.x;   // roi
    const int cb   = blockIdx.y;   // channel octet 0..7
    const int tid  = threadIdx.x;
    const int wv   = tid >> 6;     // phase1: plane index; phase2: z-sample
    const int lane = tid & 63;
    const int xb   = lane & 7;     // x-bin (covers both its x-samples)
    const int ysi  = lane >> 3;    // y-sample sub-index 0..7

    __shared__ float Bst[NPL * 16 * 8];        // [p][ys][xb] bilinear partials, 7 KB
    __shared__ float bins[16][8][8][CPAD];     // 36.9 KB

    // --- roi params (block-uniform) ---
    const float* rr = rois + r * 7;
    const int   b  = (int)rr[0];
    const float x1 = rr[1] * 0.25f, y1v = rr[2] * 0.25f, z1v = rr[3] * 0.25f;
    const float x2 = rr[4] * 0.25f, y2v = rr[5] * 0.25f, z2v = rr[6] * 0.25f;
    const float rw = fmaxf(x2 - x1, 1.0f);
    const float rh = fmaxf(y2v - y1v, 1.0f);
    const float rd = fmaxf(z2v - z1v, 1.0f);
    const float bsx = rw * 0.125f, bsy = rh * 0.125f, bsz = rd * 0.125f;

    // --- unique z-plane window ---
    const float zc0f = z1v + 0.25f * bsz, zc15f = z1v + 7.75f * bsz;
    const int p0   = (int)floorf(fminf(fmaxf(zc0f, 0.0f), 47.0f));
    const int pphi = min((int)floorf(fminf(fmaxf(zc15f, 0.0f), 47.0f)) + 1, Dd - 1);
    const int pext = pphi - p0 + 1;            // <= 13
    const bool pact = (wv < pext);

    // --- x geometry (lane-fixed), R10-proven: dwordx4 window + folded weights ---
    const float xcA = x1 + (float)xb * bsx + 0.25f * bsx;
    const float xcB = x1 + (float)xb * bsx + 0.75f * bsx;
    int xloA, xhiA, xloB, xhiB; float fxA, fxB; bool vxA, vxB;
    axis_interp(xcA, Ww, xloA, xhiA, fxA, vxA);
    axis_interp(xcB, Ww, xloB, xhiB, fxB, vxB);
    const int base = min(xloA, Ww - 4);
    float w0 = 0.0f, w1 = 0.0f, w2 = 0.0f, w3 = 0.0f;
    {
        const int iA = xloA - base, hA = xhiA - base;
        const int iB = xloB - base, hB = xhiB - base;
        const float a0 = vxA ? (1.0f - fxA) : 0.0f, a1 = vxA ? fxA : 0.0f;
        const float b0 = vxB ? (1.0f - fxB) : 0.0f, b1 = vxB ? fxB : 0.0f;
        w0 += (iA == 0) ? a0 : 0.0f; w1 += (iA == 1) ? a0 : 0.0f; w2 += (iA == 2) ? a0 : 0.0f; w3 += (iA == 3) ? a0 : 0.0f;
        w0 += (hA == 0) ? a1 : 0.0f; w1 += (hA == 1) ? a1 : 0.0f; w2 += (hA == 2) ? a1 : 0.0f; w3 += (hA == 3) ? a1 : 0.0f;
        w0 += (iB == 0) ? b0 : 0.0f; w1 += (iB == 1) ? b0 : 0.0f; w2 += (iB == 2) ? b0 : 0.0f; w3 += (iB == 3) ? b0 : 0.0f;
        w0 += (hB == 0) ? b1 : 0.0f; w1 += (hB == 1) ? b1 : 0.0f; w2 += (hB == 2) ? b1 : 0.0f; w3 += (hB == 3) ? b1 : 0.0f;
    }

    // --- y geometry per half (lane-fixed): row offsets within a plane + vy-folded weights ---
    int   o_lo[2], o_hi[2];
    float wyl[2], wyh[2];
    #pragma unroll
    for (int half = 0; half < 2; ++half) {
        const int ys = half * 8 + ysi;
        const float yc = y1v + (float)(ys >> 1) * bsy + ((float)(ys & 1) + 0.5f) * 0.5f * bsy;
        int ylo, yhi; float fy; bool vy;
        axis_interp(yc, Hh, ylo, yhi, fy, vy);
        wyl[half] = vy ? (1.0f - fy) : 0.0f;
        wyh[half] = vy ? fy : 0.0f;
        o_lo[half] = ylo * Ww + base;
        o_hi[half] = yhi * Ww + base;
    }

    // --- phase-2 z interp (wave-fixed): vz folded into wz ---
    const float zc = z1v + (float)(wv >> 1) * bsz + ((float)(wv & 1) + 0.5f) * 0.5f * bsz;
    int zlo, zhi; float fz; bool vz;
    axis_interp(zc, Dd, zlo, zhi, fz, vz);
    const float wz0 = vz ? (1.0f - fz) : 0.0f;
    const float wz1 = vz ? fz : 0.0f;
    const int   a0  = (zlo - p0) * 128 + lane;   // Bst flat: p*128 + yy*64 + lane
    const int   a1  = (zhi - p0) * 128 + lane;

    const float* fb = feats + (size_t)(b * C_TOT + cb * CSPLIT) * (size_t)DHW;
    const float* pp = fb + (size_t)(p0 + wv) * HW;   // my plane, channel 0

    // --- prefetch channel 0 rows ---
    f4v R0 = {0,0,0,0}, R1 = {0,0,0,0}, R2 = {0,0,0,0}, R3 = {0,0,0,0};
    if (pact) {
        R0 = *(const f4v*)(pp + o_lo[0]);
        R1 = *(const f4v*)(pp + o_hi[0]);
        R2 = *(const f4v*)(pp + o_lo[1]);
        R3 = *(const f4v*)(pp + o_hi[1]);
    }

    const bool writer = !(ysi & 1);
    const int  ybl    = ysi >> 1;

    for (int c = 0; c < CSPLIT; ++c) {
        // --- phase 1 compute: xy-bilinear, x-pair-folded, per unique plane ---
        float B0 = 0.0f, B1 = 0.0f;
        if (pact) {
            B0 = wyl[0] * dot4(R0, w0, w1, w2, w3) + wyh[0] * dot4(R1, w0, w1, w2, w3);
            B1 = wyl[1] * dot4(R2, w0, w1, w2, w3) + wyh[1] * dot4(R3, w0, w1, w2, w3);
        }
        // prefetch channel c+1 (flies across the two barriers + phase 2)
        if (c + 1 < CSPLIT) {
            pp += DHW;
            if (pact) {
                R0 = *(const f4v*)(pp + o_lo[0]);
                R1 = *(const f4v*)(pp + o_hi[0]);
                R2 = *(const f4v*)(pp + o_lo[1]);
                R3 = *(const f4v*)(pp + o_hi[1]);
            }
        }
        __syncthreads();   // Bst(c-1) fully consumed by phase 2 of prev iter
        if (pact) {
            Bst[wv * 128 +      lane] = B0;   // [p][ys=ysi  ][xb] — stride-1
            Bst[wv * 128 + 64 + lane] = B1;   // [p][ys=8+ysi][xb]
        }
        __syncthreads();   // Bst(c) visible

        // --- phase 2: z-combine two plane slices (wave-uniform planes, stride-1 reads) ---
        #pragma unroll
        for (int yy = 0; yy < 2; ++yy) {
            float v = wz0 * Bst[a0 + yy * 64] + wz1 * Bst[a1 + yy * 64];
            v += __shfl_xor(v, 8);            // reduce y-sample pair
            if (writer)
                bins[wv][yy * 4 + ybl][xb][c] = v;
        }
    }
    __syncthreads();

    // --- fused pooling: out(dz,h,w) = (1/64) * sum over 4 z-slices, 2 yb, 2 xb ---
    for (int i = tid; i < CSPLIT * 7 * 7 * 7; i += 1024) {
        const int w  = i % 7;
        const int h  = (i / 7) % 7;
        const int dz = (i / 49) % 7;
        const int c  = i / 343;
        float acc = 0.0f;
        #pragma unroll
        for (int g = 0; g < 4; ++g) {
            const int z = 2 * dz + g;
            acc += bins[z][h    ][w][c] + bins[z][h    ][w + 1][c]
                 + bins[z][h + 1][w][c] + bins[z][h + 1][w + 1][c];
        }
        acc *= (1.0f / 64.0f);
        const int cg = cb * CSPLIT + c;
        out[((((size_t)r * C_TOT + cg) * 7 + dz) * 7 + h) * 7 + w] = acc;
    }
}

extern "C" void kernel_launch(void* const* d_in, const int* in_sizes, int n_in,
                              void* d_out, int out_size, void* d_ws, size_t ws_size,
                              hipStream_t stream) {
    const float* feats = (const float*)d_in[0];
    const float* rois  = (const float*)d_in[1];
    float* out = (float*)d_out;
    const int R = in_sizes[1] / 7;   // 64
    dim3 grid(R, C_TOT / CSPLIT);
    roialign_avg3d_kernel<<<grid, 1024, 0, stream>>>(feats, rois, out);
}